// Round 1
// baseline (15.394 us; speedup 1.0000x reference)
//
#include <hip/hip_runtime.h>
#include <cfloat>
#include <cmath>

#define RS 7   // ROI pool output size

// features: (B=2, C=256, H=50, W=50) f32
// boxes:    (B=2, Nb=64, 4) f32  -> N=128 boxes
// out:      (N=128, C=256, 7, 7) f32
__global__ void roi_pool_kernel(const float* __restrict__ features,
                                const float* __restrict__ boxes,
                                const int* __restrict__ image_size_p,
                                float* __restrict__ out,
                                int total) {
    int idx = blockIdx.x * blockDim.x + threadIdx.x;
    if (idx >= total) return;

    const int C = 256, H = 50, W = 50, Nb = 64;

    int j = idx % RS;
    int t = idx / RS;
    int i = t % RS;
    t /= RS;
    int c = t % C;
    int n = t / C;           // 0..127
    int b = n / Nb;          // batch index

    float img = (float)image_size_p[0];
    float scale_h = (float)H / img;   // 50/800 = 0.0625 exact
    float scale_w = (float)W / img;

    const float* bb = boxes + (size_t)n * 4;
    float x = bb[0], y = bb[1], w = bb[2], h = bb[3];

    // jnp.round = round half to even = rintf (default FE_TONEAREST)
    int x1 = max(0, (int)rintf(x * scale_w));
    int y1 = max(0, (int)rintf(y * scale_h));
    int x2 = min(W, (int)rintf((x + w) * scale_w) + 1);
    int y2 = min(H, (int)rintf((y + h) * scale_h) + 1);
    if (x2 <= x1) x2 = min(x1 + 1, W);
    if (y2 <= y1) y2 = min(y1 + 1, H);

    int rh = y2 - y1;
    int rw = x2 - x1;

    // bin bounds (floor/ceil division; rh, rw > 0)
    int hs = y1 + (i * rh) / RS;
    int he = y1 + ((i + 1) * rh + RS - 1) / RS;
    int ws = x1 + (j * rw) / RS;
    int we = x1 + ((j + 1) * rw + RS - 1) / RS;

    const float* fplane = features + ((size_t)b * C + c) * (size_t)(H * W);
    float m = -FLT_MAX;
    for (int r = hs; r < he; ++r) {
        const float* row = fplane + r * W;
        for (int q = ws; q < we; ++q) {
            m = fmaxf(m, row[q]);
        }
    }
    out[idx] = m;
}

extern "C" void kernel_launch(void* const* d_in, const int* in_sizes, int n_in,
                              void* d_out, int out_size, void* d_ws, size_t ws_size,
                              hipStream_t stream) {
    const float* features = (const float*)d_in[0];
    const float* boxes    = (const float*)d_in[1];
    const int*   img_sz   = (const int*)d_in[2];
    float* out = (float*)d_out;

    int total = out_size;               // 128 * 256 * 7 * 7 = 1,605,632
    int block = 256;
    int grid = (total + block - 1) / block;
    roi_pool_kernel<<<grid, block, 0, stream>>>(features, boxes, img_sz, out, total);
}